// Round 11
// baseline (480.512 us; speedup 1.0000x reference)
//
#include <hip/hip_runtime.h>

typedef unsigned short u16;
typedef __attribute__((ext_vector_type(8)))  short bf16x8;
typedef __attribute__((ext_vector_type(4)))  float f32x4;
typedef __attribute__((ext_vector_type(16))) float f32x16;

#define NROWS 131072
#define NMOL  2048
#define CIN   128
#define HDIM  1024
#define EMBSTRIDE 1152   // 9*128

#define KT1 (CIN  / 16)   // 8
#define NT  (HDIM / 32)   // 32

#define BM2 256
#define BN2 256
#define NRB (NROWS / BM2) // 512
#define NCB (HDIM  / BN2) // 4
#define NKT 16            // K-tiles of 64

// ---------- helpers ----------
__device__ __forceinline__ u16 f2bf(float f) {
    union { float f; unsigned u; } v; v.f = f;
    unsigned u = v.u;
    u += 0x7FFFu + ((u >> 16) & 1u);   // round-to-nearest-even
    return (u16)(u >> 16);
}

__device__ __forceinline__ float silu_f(float v) {
    float e = __expf(-v);
    return v * __builtin_amdgcn_rcpf(1.0f + e);
}

__device__ __forceinline__ f32x16 mfma32(bf16x8 a, bf16x8 b, f32x16 c) {
    return __builtin_amdgcn_mfma_f32_32x32x16_bf16(a, b, c, 0, 0, 0);
}
__device__ __forceinline__ f32x4 mfma16(bf16x8 a, bf16x8 b, f32x4 c) {
    return __builtin_amdgcn_mfma_f32_16x16x32_bf16(a, b, c, 0, 0, 0);
}

// wave-uniform LDS dest; HW scatters lane l to (dest + l*16B). global src is per-lane.
__device__ __forceinline__ void gload_lds16(const u16* g, u16* lds_base) {
    __builtin_amdgcn_global_load_lds(
        (const __attribute__((address_space(1))) unsigned int*)g,
        (__attribute__((address_space(3))) unsigned int*)lds_base,
        16, 0, 0);
}

// ---------- pack W (K x N fp32) into 32x32x16 B-frags (for GEMM1) ----------
// frag id = kt*NT + nt. lane l, elem j -> W[kt*16 + (l>>5)*8 + j][nt*32 + (l&31)]
__global__ void pack_w32(const float* __restrict__ W, u16* __restrict__ dst, int K, int N) {
    int tid  = blockIdx.x * blockDim.x + threadIdx.x;
    int lane = tid & 63;
    int frag = tid >> 6;
    int NTl = N >> 5;
    int KTl = K >> 4;
    if (frag >= KTl * NTl) return;
    int kt = frag / NTl;
    int nt = frag - kt * NTl;
    int col  = (nt << 5) + (lane & 31);
    int krow = (kt << 4) + ((lane >> 5) << 3);
    __align__(16) u16 tmp[8];
    #pragma unroll
    for (int j = 0; j < 8; ++j) tmp[j] = f2bf(W[(size_t)(krow + j) * N + col]);
    *reinterpret_cast<uint4*>(dst + (size_t)tid * 8) = *reinterpret_cast<uint4*>(tmp);
}

// ---------- pack W (K x N fp32) into 16x16x32 B-frags (for GEMM2) ----------
// frag id = k32*(N/16) + n16. lane l, elem j -> W[k32*32 + (l>>4)*8 + j][n16*16 + (l&15)]
__global__ void pack_w16(const float* __restrict__ W, u16* __restrict__ dst, int K, int N) {
    int tid  = blockIdx.x * blockDim.x + threadIdx.x;
    int lane = tid & 63;
    int frag = tid >> 6;
    int NT16 = N >> 4;
    int KT32 = K >> 5;
    if (frag >= KT32 * NT16) return;
    int k32 = frag / NT16;
    int n16 = frag - k32 * NT16;
    int col  = (n16 << 4) + (lane & 15);
    int krow = (k32 << 5) + ((lane >> 4) << 3);
    __align__(16) u16 tmp[8];
    #pragma unroll
    for (int j = 0; j < 8; ++j) tmp[j] = f2bf(W[(size_t)(krow + j) * N + col]);
    *reinterpret_cast<uint4*>(dst + (size_t)tid * 8) = *reinterpret_cast<uint4*>(tmp);
}

// ---------- K1: h1 = silu(x @ W1 + b1), written as packed 16x16x32 A-fragments ----------
// h1f frag id = m16_global*32 + k32 ; lane l, j -> h1[m16*16 + (l&15)][k32*32 + (l>>4)*8 + j]
__global__ __launch_bounds__(512, 2) void gemm1_pack(
    const float* __restrict__ emb,
    const u16*  __restrict__ w1f,
    const float* __restrict__ b1,
    u16* __restrict__ h1f)
{
    __shared__ u16 x_lds[64][CIN + 8];       // 17.4 KB
    __shared__ u16 h1_lds[64][HDIM + 8];     // 132 KB

    const int tid  = threadIdx.x;
    const int lane = tid & 63;
    const int w    = tid >> 6;
    const int l31  = lane & 31;
    const int lhi  = lane >> 5;
    const int l15  = lane & 15;
    const int l4   = lane >> 4;
    const int row0 = blockIdx.x * 64;

    // stage x tile as bf16
    {
        int r   = tid >> 3;
        int seg = tid & 7;
        const float4* s4 = reinterpret_cast<const float4*>(
            emb + (size_t)(row0 + r) * EMBSTRIDE + seg * 16);
        __align__(16) u16 u[16];
        #pragma unroll
        for (int i = 0; i < 4; ++i) {
            float4 f = s4[i];
            u[i*4+0] = f2bf(f.x); u[i*4+1] = f2bf(f.y);
            u[i*4+2] = f2bf(f.z); u[i*4+3] = f2bf(f.w);
        }
        uint4* d = reinterpret_cast<uint4*>(&x_lds[r][seg * 16]);
        d[0] = reinterpret_cast<uint4*>(u)[0];
        d[1] = reinterpret_cast<uint4*>(u)[1];
    }

    auto LDB1 = [&](int kt, bf16x8* b) {
        #pragma unroll
        for (int nti = 0; nti < 4; ++nti)
            b[nti] = *reinterpret_cast<const bf16x8*>(
                w1f + (((size_t)kt * NT + 4 * w + nti) * 64 + lane) * 8);
    };

    bf16x8 bC[4], bN[4];
    LDB1(0, bC);
    __syncthreads();

    f32x16 acc1[2][4];
    #pragma unroll
    for (int mt = 0; mt < 2; ++mt)
        #pragma unroll
        for (int nti = 0; nti < 4; ++nti)
            #pragma unroll
            for (int r = 0; r < 16; ++r) acc1[mt][nti][r] = 0.0f;

    #pragma unroll
    for (int kt = 0; kt < KT1; ++kt) {
        if (kt + 1 < KT1) LDB1(kt + 1, bN);
        bf16x8 a[2];
        #pragma unroll
        for (int mt = 0; mt < 2; ++mt)
            a[mt] = *reinterpret_cast<const bf16x8*>(
                &x_lds[mt*32 + l31][kt*16 + (lhi << 3)]);
        #pragma unroll
        for (int nti = 0; nti < 4; ++nti)
            #pragma unroll
            for (int mt = 0; mt < 2; ++mt)
                acc1[mt][nti] = mfma32(a[mt], bC[nti], acc1[mt][nti]);
        if (kt + 1 < KT1) {
            #pragma unroll
            for (int i = 0; i < 4; ++i) bC[i] = bN[i];
        }
    }

    // silu -> bf16 -> h1_lds  (32x32 C/D: col=lane&31, row=(r&3)+8*(r>>2)+4*lhi)
    #pragma unroll
    for (int nti = 0; nti < 4; ++nti) {
        int col = w*128 + nti*32 + l31;
        float bias = b1[col];
        #pragma unroll
        for (int mt = 0; mt < 2; ++mt)
            #pragma unroll
            for (int r = 0; r < 16; ++r) {
                int row = mt*32 + (r & 3) + 8*(r >> 2) + 4*lhi;
                h1_lds[row][col] = f2bf(silu_f(acc1[mt][nti][r] + bias));
            }
    }
    // pack-out in 16x16 A-frag order; wave owns k32 = 4w..4w+3 (its own cols -> no barrier)
    const size_t m0 = (size_t)blockIdx.x * 4;
    #pragma unroll
    for (int m16l = 0; m16l < 4; ++m16l)
        #pragma unroll
        for (int kk = 0; kk < 4; ++kk) {
            int k32 = w*4 + kk;
            bf16x8 v = *reinterpret_cast<const bf16x8*>(
                &h1_lds[m16l*16 + l15][k32*32 + (l4 << 3)]);
            *reinterpret_cast<bf16x8*>(
                h1f + ((m0 + m16l)*32 + k32)*512 + (size_t)lane*8) = v;
        }
}

// ---- one 8-phase-style phase: [stage quarter] + 12 ds_read + 16 MFMA ----
#define PHASE(MHc, NHc, PIDX)                                                     \
  {                                                                               \
    const int MH = (MHc), NH = (NHc);                                             \
    if (st && (PIDX) < 2) {                                                       \
      _Pragma("unroll")                                                           \
      for (int i = 0; i < 4; ++i) stage_slot((PIDX)*32 + w*4 + i, t + 1, nx);     \
    }                                                                             \
    bf16x8 Af[4][2], Bf[2][2];                                                    \
    _Pragma("unroll")                                                             \
    for (int mi = 0; mi < 4; ++mi)                                                \
      _Pragma("unroll")                                                           \
      for (int kt = 0; kt < 2; ++kt)                                              \
        Af[mi][kt] = *reinterpret_cast<const bf16x8*>(                            \
            &ab[cur][(size_t)(((wr*8 + MH*4 + mi)*2 + kt))*512 + (size_t)lane*8]);\
    _Pragma("unroll")                                                             \
    for (int ni = 0; ni < 2; ++ni)                                                \
      _Pragma("unroll")                                                           \
      for (int kt = 0; kt < 2; ++kt)                                              \
        Bf[ni][kt] = *reinterpret_cast<const bf16x8*>(                            \
            &ab[cur][(size_t)(32 + kt*16 + wc*4 + NH*2 + ni)*512 + (size_t)lane*8]);\
    asm volatile("s_waitcnt lgkmcnt(0)" ::: "memory");                            \
    __builtin_amdgcn_sched_barrier(0);                                            \
    __builtin_amdgcn_s_setprio(1);                                                \
    _Pragma("unroll")                                                             \
    for (int kt = 0; kt < 2; ++kt)                                                \
      _Pragma("unroll")                                                           \
      for (int ni = 0; ni < 2; ++ni)                                              \
        _Pragma("unroll")                                                         \
        for (int mi = 0; mi < 4; ++mi)                                            \
          acc[MH*4+mi][NH*2+ni] = mfma16(Af[mi][kt], Bf[ni][kt],                  \
                                         acc[MH*4+mi][NH*2+ni]);                  \
    __builtin_amdgcn_s_setprio(0);                                                \
    __builtin_amdgcn_sched_barrier(0);                                            \
  }

// ---------- K2: 8-phase-style GEMM2: h2 = silu(h1 @ W2 + b2), fold W3 ----------
// BM2=256 x BN2=256, BK=64, 16 K-tiles, 16x16x32 MFMA.
// 8 waves: wr=w>>2 (2 x 128 rows), wc=w&3 (4 x 64 cols); acc[8][4] f32x4 = 128 VGPR.
// LDS: 2 x 64KB frag-packed dbuf. Per K-tile 4 phases; staging in phases 0-1;
// one vmcnt(0)+s_barrier per K-tile (loads are >=2 phases old -> cheap drain).
__global__ __launch_bounds__(512, 2) void gemm2_energy(
    const u16*  __restrict__ h1f,
    const u16*  __restrict__ w2f,
    const float* __restrict__ b2,
    const float* __restrict__ w3,
    float* __restrict__ e_part)
{
    __shared__ u16 ab[2][64 * 512];          // 128 KB
    __shared__ float e_red[8][128];          // 4 KB

    const int tid  = threadIdx.x;
    const int lane = tid & 63;
    const int w    = tid >> 6;
    const int l15  = lane & 15;
    const int l4   = lane >> 4;              // 0..3
    const int wr   = w >> 2;                 // 2 row groups x 128 rows
    const int wc   = w & 3;                  // 4 col groups x 64 cols

    const int wg = blockIdx.x;               // 2048 wgs; bijective XCD swizzle
    const int rb = (wg & 7) + 8 * ((wg >> 3) >> 2);
    const int cb = (wg >> 3) & 3;

    // LDS slot map: s<32: A (m16l=s>>1, kt=s&1) ; s>=32: B (kt=(s-32)>>4, n16l=(s-32)&15)
    auto stage_slot = [&](int slot, int tile, int buf) {
        const u16* src;
        if (slot < 32)
            src = h1f + (((size_t)rb*16 + (slot >> 1))*32
                         + (size_t)(tile*2 + (slot & 1)))*512 + (size_t)lane*8;
        else {
            const int q = slot - 32;
            src = w2f + (((size_t)(tile*2 + (q >> 4)))*64 + cb*16 + (q & 15))*512
                      + (size_t)lane*8;
        }
        gload_lds16(src, &ab[buf][(size_t)slot * 512]);
    };

    f32x4 acc[8][4];
    #pragma unroll
    for (int mi = 0; mi < 8; ++mi)
        #pragma unroll
        for (int ni = 0; ni < 4; ++ni)
            #pragma unroll
            for (int r = 0; r < 4; ++r) acc[mi][ni][r] = 0.0f;

    // prologue: stage tile 0 fully (8 slots per wave)
    #pragma unroll
    for (int i = 0; i < 8; ++i) stage_slot(w*8 + i, 0, 0);
    asm volatile("s_waitcnt vmcnt(0)" ::: "memory");
    __builtin_amdgcn_sched_barrier(0);
    __builtin_amdgcn_s_barrier();

    for (int t = 0; t < NKT; ++t) {
        const int cur = t & 1;
        const int nx  = cur ^ 1;
        const bool st = (t + 1 < NKT);
        PHASE(0, 0, 0)
        PHASE(0, 1, 1)
        PHASE(1, 0, 2)
        PHASE(1, 1, 3)
        if (st) {
            asm volatile("s_waitcnt vmcnt(0)" ::: "memory");
            __builtin_amdgcn_sched_barrier(0);
            __builtin_amdgcn_s_barrier();
        }
    }

    // epilogue: silu + dot W3 -> per-row energy; rows: wr*128 + mi*16 + l4*4 + r
    {
        float e16[8][4];
        #pragma unroll
        for (int mi = 0; mi < 8; ++mi)
            #pragma unroll
            for (int r = 0; r < 4; ++r) e16[mi][r] = 0.0f;

        #pragma unroll
        for (int ni = 0; ni < 4; ++ni) {
            int col = cb*256 + wc*64 + ni*16 + l15;
            float bias = b2[col];
            float w3v  = w3[col];
            #pragma unroll
            for (int mi = 0; mi < 8; ++mi)
                #pragma unroll
                for (int r = 0; r < 4; ++r)
                    e16[mi][r] += silu_f(acc[mi][ni][r] + bias) * w3v;
        }

        // reduce across the 16 col-lanes (keeps l4 intact)
        #pragma unroll
        for (int off = 1; off < 16; off <<= 1)
            #pragma unroll
            for (int mi = 0; mi < 8; ++mi)
                #pragma unroll
                for (int r = 0; r < 4; ++r)
                    e16[mi][r] += __shfl_xor(e16[mi][r], off, 64);

        if (l15 == 0) {
            #pragma unroll
            for (int mi = 0; mi < 8; ++mi)
                #pragma unroll
                for (int r = 0; r < 4; ++r)
                    e_red[w][mi*16 + l4*4 + r] = e16[mi][r];
        }
    }
    __syncthreads();

    // fold 4 wc-partials per row; threads 0..255 handle the 256 rows
    if (tid < 256) {
        const int wrg = tid >> 7;
        const int rr  = tid & 127;
        float s = 0.0f;
        #pragma unroll
        for (int wci = 0; wci < 4; ++wci) s += e_red[wrg*4 + wci][rr];
        e_part[(size_t)cb * NROWS + (size_t)rb * 256 + wrg*128 + rr] = s;
    }
}

// ---------- deterministic segment sum over sorted batch, folding 4 cb slabs + b3 ----------
__global__ void segsum(const float* __restrict__ e_part,
                       const int* __restrict__ batch,
                       const float* __restrict__ b3,
                       float* __restrict__ out)
{
    int mol  = blockIdx.x;
    int lane = threadIdx.x;          // 64 threads

    int lo = 0, hi = NROWS;
    while (lo < hi) { int mid = (lo + hi) >> 1; if (batch[mid] < mol)     lo = mid + 1; else hi = mid; }
    int start = lo;
    lo = start; hi = NROWS;
    while (lo < hi) { int mid = (lo + hi) >> 1; if (batch[mid] < mol + 1) lo = mid + 1; else hi = mid; }
    int end = lo;

    float b3v = b3[0];
    float s = 0.0f;
    for (int i = start + lane; i < end; i += 64) {
        float v = b3v;
        #pragma unroll
        for (int sl = 0; sl < 4; ++sl) v += e_part[(size_t)sl * NROWS + i];
        s += v;
    }
    #pragma unroll
    for (int off = 32; off; off >>= 1) s += __shfl_xor(s, off, 64);
    if (lane == 0) out[mol] = s;
}

// ---------- launch ----------
extern "C" void kernel_launch(void* const* d_in, const int* in_sizes, int n_in,
                              void* d_out, int out_size, void* d_ws, size_t ws_size,
                              hipStream_t stream) {
    const float* emb = (const float*)d_in[0];
    const float* W1  = (const float*)d_in[1];
    const float* b1  = (const float*)d_in[2];
    const float* W2  = (const float*)d_in[3];
    const float* b2  = (const float*)d_in[4];
    const float* W3  = (const float*)d_in[5];
    const float* b3  = (const float*)d_in[6];
    const int*   batch = (const int*)d_in[7];

    char* ws = (char*)d_ws;
    u16*   w1f    = (u16*)ws;                                  // 256 KB (32x32 frags)
    u16*   w2f    = (u16*)(ws + 262144);                       // 2 MB  (16x16 frags)
    u16*   h1f    = (u16*)(ws + 2359296);                      // 256 MB (16x16 A-frags)
    float* e_part = (float*)(ws + 2359296 + 268435456);        // 2 MB (4 slabs)

    pack_w32<<<64,  256, 0, stream>>>(W1, w1f, CIN,  HDIM);
    pack_w16<<<512, 256, 0, stream>>>(W2, w2f, HDIM, HDIM);
    gemm1_pack<<<NROWS / 64, 512, 0, stream>>>(emb, w1f, b1, h1f);
    gemm2_energy<<<NRB * NCB, 512, 0, stream>>>(h1f, w2f, b2, W3, e_part);
    segsum<<<NMOL, 64, 0, stream>>>(e_part, batch, b3, (float*)d_out);
}

// Round 12
// 446.198 us; speedup vs baseline: 1.0769x; 1.0769x over previous
//
#include <hip/hip_runtime.h>

typedef unsigned short u16;
typedef __attribute__((ext_vector_type(8)))  short bf16x8;
typedef __attribute__((ext_vector_type(4)))  float f32x4;
typedef __attribute__((ext_vector_type(16))) float f32x16;

#define NROWS 131072
#define NMOL  2048
#define CIN   128
#define HDIM  1024
#define EMBSTRIDE 1152   // 9*128

#define KT1 (CIN  / 16)   // 8
#define NT  (HDIM / 32)   // 32

#define BM2 256
#define BN2 256
#define NRB (NROWS / BM2) // 512
#define NCB (HDIM  / BN2) // 4
#define NKT 16            // K-tiles of 64

// ---------- helpers ----------
__device__ __forceinline__ u16 f2bf(float f) {
    union { float f; unsigned u; } v; v.f = f;
    unsigned u = v.u;
    u += 0x7FFFu + ((u >> 16) & 1u);   // round-to-nearest-even
    return (u16)(u >> 16);
}

__device__ __forceinline__ float silu_f(float v) {
    float e = __expf(-v);
    return v * __builtin_amdgcn_rcpf(1.0f + e);
}

__device__ __forceinline__ f32x16 mfma32(bf16x8 a, bf16x8 b, f32x16 c) {
    return __builtin_amdgcn_mfma_f32_32x32x16_bf16(a, b, c, 0, 0, 0);
}
__device__ __forceinline__ f32x4 mfma16(bf16x8 a, bf16x8 b, f32x4 c) {
    return __builtin_amdgcn_mfma_f32_16x16x32_bf16(a, b, c, 0, 0, 0);
}

// wave-uniform LDS dest; HW scatters lane l to (dest + l*16B). global src is per-lane.
__device__ __forceinline__ void gload_lds16(const u16* g, u16* lds_base) {
    __builtin_amdgcn_global_load_lds(
        (const __attribute__((address_space(1))) unsigned int*)g,
        (__attribute__((address_space(3))) unsigned int*)lds_base,
        16, 0, 0);
}

// ---------- pack W (K x N fp32) into 32x32x16 B-frags (for GEMM1) ----------
// frag id = kt*NT + nt. lane l, elem j -> W[kt*16 + (l>>5)*8 + j][nt*32 + (l&31)]
__global__ void pack_w32(const float* __restrict__ W, u16* __restrict__ dst, int K, int N) {
    int tid  = blockIdx.x * blockDim.x + threadIdx.x;
    int lane = tid & 63;
    int frag = tid >> 6;
    int NTl = N >> 5;
    int KTl = K >> 4;
    if (frag >= KTl * NTl) return;
    int kt = frag / NTl;
    int nt = frag - kt * NTl;
    int col  = (nt << 5) + (lane & 31);
    int krow = (kt << 4) + ((lane >> 5) << 3);
    __align__(16) u16 tmp[8];
    #pragma unroll
    for (int j = 0; j < 8; ++j) tmp[j] = f2bf(W[(size_t)(krow + j) * N + col]);
    *reinterpret_cast<uint4*>(dst + (size_t)tid * 8) = *reinterpret_cast<uint4*>(tmp);
}

// ---------- pack W (K x N fp32) into 16x16x32 B-frags (for GEMM2) ----------
// frag id = k32*(N/16) + n16. lane l, elem j -> W[k32*32 + (l>>4)*8 + j][n16*16 + (l&15)]
__global__ void pack_w16(const float* __restrict__ W, u16* __restrict__ dst, int K, int N) {
    int tid  = blockIdx.x * blockDim.x + threadIdx.x;
    int lane = tid & 63;
    int frag = tid >> 6;
    int NT16 = N >> 4;
    int KT32 = K >> 5;
    if (frag >= KT32 * NT16) return;
    int k32 = frag / NT16;
    int n16 = frag - k32 * NT16;
    int col  = (n16 << 4) + (lane & 15);
    int krow = (k32 << 5) + ((lane >> 4) << 3);
    __align__(16) u16 tmp[8];
    #pragma unroll
    for (int j = 0; j < 8; ++j) tmp[j] = f2bf(W[(size_t)(krow + j) * N + col]);
    *reinterpret_cast<uint4*>(dst + (size_t)tid * 8) = *reinterpret_cast<uint4*>(tmp);
}

// ---------- K1: h1 = silu(x @ W1 + b1), written as packed 16x16x32 A-fragments ----------
// h1f frag id = m16_global*32 + k32 ; lane l, j -> h1[m16*16 + (l&15)][k32*32 + (l>>4)*8 + j]
__global__ __launch_bounds__(512, 2) void gemm1_pack(
    const float* __restrict__ emb,
    const u16*  __restrict__ w1f,
    const float* __restrict__ b1,
    u16* __restrict__ h1f)
{
    __shared__ u16 x_lds[64][CIN + 8];       // 17.4 KB
    __shared__ u16 h1_lds[64][HDIM + 8];     // 132 KB

    const int tid  = threadIdx.x;
    const int lane = tid & 63;
    const int w    = tid >> 6;
    const int l31  = lane & 31;
    const int lhi  = lane >> 5;
    const int l15  = lane & 15;
    const int l4   = lane >> 4;
    const int row0 = blockIdx.x * 64;

    // stage x tile as bf16
    {
        int r   = tid >> 3;
        int seg = tid & 7;
        const float4* s4 = reinterpret_cast<const float4*>(
            emb + (size_t)(row0 + r) * EMBSTRIDE + seg * 16);
        __align__(16) u16 u[16];
        #pragma unroll
        for (int i = 0; i < 4; ++i) {
            float4 f = s4[i];
            u[i*4+0] = f2bf(f.x); u[i*4+1] = f2bf(f.y);
            u[i*4+2] = f2bf(f.z); u[i*4+3] = f2bf(f.w);
        }
        uint4* d = reinterpret_cast<uint4*>(&x_lds[r][seg * 16]);
        d[0] = reinterpret_cast<uint4*>(u)[0];
        d[1] = reinterpret_cast<uint4*>(u)[1];
    }

    auto LDB1 = [&](int kt, bf16x8* b) {
        #pragma unroll
        for (int nti = 0; nti < 4; ++nti)
            b[nti] = *reinterpret_cast<const bf16x8*>(
                w1f + (((size_t)kt * NT + 4 * w + nti) * 64 + lane) * 8);
    };

    bf16x8 bC[4], bN[4];
    LDB1(0, bC);
    __syncthreads();

    f32x16 acc1[2][4];
    #pragma unroll
    for (int mt = 0; mt < 2; ++mt)
        #pragma unroll
        for (int nti = 0; nti < 4; ++nti)
            #pragma unroll
            for (int r = 0; r < 16; ++r) acc1[mt][nti][r] = 0.0f;

    #pragma unroll
    for (int kt = 0; kt < KT1; ++kt) {
        if (kt + 1 < KT1) LDB1(kt + 1, bN);
        bf16x8 a[2];
        #pragma unroll
        for (int mt = 0; mt < 2; ++mt)
            a[mt] = *reinterpret_cast<const bf16x8*>(
                &x_lds[mt*32 + l31][kt*16 + (lhi << 3)]);
        #pragma unroll
        for (int nti = 0; nti < 4; ++nti)
            #pragma unroll
            for (int mt = 0; mt < 2; ++mt)
                acc1[mt][nti] = mfma32(a[mt], bC[nti], acc1[mt][nti]);
        if (kt + 1 < KT1) {
            #pragma unroll
            for (int i = 0; i < 4; ++i) bC[i] = bN[i];
        }
    }

    // silu -> bf16 -> h1_lds  (32x32 C/D: col=lane&31, row=(r&3)+8*(r>>2)+4*lhi)
    #pragma unroll
    for (int nti = 0; nti < 4; ++nti) {
        int col = w*128 + nti*32 + l31;
        float bias = b1[col];
        #pragma unroll
        for (int mt = 0; mt < 2; ++mt)
            #pragma unroll
            for (int r = 0; r < 16; ++r) {
                int row = mt*32 + (r & 3) + 8*(r >> 2) + 4*lhi;
                h1_lds[row][col] = f2bf(silu_f(acc1[mt][nti][r] + bias));
            }
    }
    // pack-out in 16x16 A-frag order; wave owns k32 = 4w..4w+3 (its own cols -> no barrier)
    const size_t m0 = (size_t)blockIdx.x * 4;
    #pragma unroll
    for (int m16l = 0; m16l < 4; ++m16l)
        #pragma unroll
        for (int kk = 0; kk < 4; ++kk) {
            int k32 = w*4 + kk;
            bf16x8 v = *reinterpret_cast<const bf16x8*>(
                &h1_lds[m16l*16 + l15][k32*32 + (l4 << 3)]);
            *reinterpret_cast<bf16x8*>(
                h1f + ((m0 + m16l)*32 + k32)*512 + (size_t)lane*8) = v;
        }
}

// ---------- K2: GEMM2 with minimal-LDS-read 2-phase interleave per K-tile ----------
// BM2=256 x BN2=256, BK=64, 16 K-tiles, 16x16x32 MFMA.
// 8 waves: wr=w>>2 (2 x 128 rows), wc=w&3 (4 x 64 cols); acc[8][4] f32x4 = 128 regs.
// Per K-tile per wave: 24 ds_read_b128 (MINIMAL: B 8 held across tile, A 8 per half),
// 64 MFMA in two setprio clusters. LDS: 2 x 64KB frag-packed dbuf.
__global__ __launch_bounds__(512, 2) void gemm2_energy(
    const u16*  __restrict__ h1f,
    const u16*  __restrict__ w2f,
    const float* __restrict__ b2,
    const float* __restrict__ w3,
    float* __restrict__ e_part)
{
    __shared__ u16 ab[2][64 * 512];          // 128 KB
    __shared__ float e_red[8][128];          // 4 KB

    const int tid  = threadIdx.x;
    const int lane = tid & 63;
    const int w    = tid >> 6;
    const int l15  = lane & 15;
    const int l4   = lane >> 4;              // 0..3
    const int wr   = w >> 2;                 // 2 row groups x 128 rows
    const int wc   = w & 3;                  // 4 col groups x 64 cols

    const int wg = blockIdx.x;               // 2048 wgs; bijective XCD swizzle
    const int rb = (wg & 7) + 8 * ((wg >> 3) >> 2);
    const int cb = (wg >> 3) & 3;

    // LDS slot map: s<32: A (m16l=s>>1, kt=s&1) ; s>=32: B (kt=(s-32)>>4, n16l=(s-32)&15)
    auto stage_slot = [&](int slot, int tile, int buf) {
        const u16* src;
        if (slot < 32)
            src = h1f + (((size_t)rb*16 + (slot >> 1))*32
                         + (size_t)(tile*2 + (slot & 1)))*512 + (size_t)lane*8;
        else {
            const int q = slot - 32;
            src = w2f + (((size_t)(tile*2 + (q >> 4)))*64 + cb*16 + (q & 15))*512
                      + (size_t)lane*8;
        }
        gload_lds16(src, &ab[buf][(size_t)slot * 512]);
    };

    f32x4 acc[8][4];
    #pragma unroll
    for (int mi = 0; mi < 8; ++mi)
        #pragma unroll
        for (int ni = 0; ni < 4; ++ni)
            #pragma unroll
            for (int r = 0; r < 4; ++r) acc[mi][ni][r] = 0.0f;

    // prologue: stage tile 0 fully (8 slots per wave)
    #pragma unroll
    for (int i = 0; i < 8; ++i) stage_slot(w*8 + i, 0, 0);
    asm volatile("s_waitcnt vmcnt(0)" ::: "memory");
    __builtin_amdgcn_sched_barrier(0);
    __builtin_amdgcn_s_barrier();

    for (int t = 0; t < NKT; ++t) {
        const int cur = t & 1;
        const int nx  = cur ^ 1;
        const bool st = (t + 1 < NKT);

        bf16x8 Bf[4][2];   // all B frags for this wave's 64 cols, both kt — held across tile
        bf16x8 Af[4][2];   // A frags for one MH half (reused across halves)

        // ---- phase 0: stage A-half of next tile; read B(all) + A(MH=0); 32 MFMA ----
        if (st) {
            #pragma unroll
            for (int i = 0; i < 4; ++i) stage_slot(w*4 + i, t + 1, nx);
        }
        #pragma unroll
        for (int ni = 0; ni < 4; ++ni)
            #pragma unroll
            for (int kt = 0; kt < 2; ++kt)
                Bf[ni][kt] = *reinterpret_cast<const bf16x8*>(
                    &ab[cur][(size_t)(32 + kt*16 + wc*4 + ni)*512 + (size_t)lane*8]);
        #pragma unroll
        for (int mi = 0; mi < 4; ++mi)
            #pragma unroll
            for (int kt = 0; kt < 2; ++kt)
                Af[mi][kt] = *reinterpret_cast<const bf16x8*>(
                    &ab[cur][(size_t)((wr*8 + mi)*2 + kt)*512 + (size_t)lane*8]);
        asm volatile("s_waitcnt lgkmcnt(0)" ::: "memory");
        __builtin_amdgcn_sched_barrier(0);
        __builtin_amdgcn_s_setprio(1);
        #pragma unroll
        for (int kt = 0; kt < 2; ++kt)
            #pragma unroll
            for (int ni = 0; ni < 4; ++ni)
                #pragma unroll
                for (int mi = 0; mi < 4; ++mi)
                    acc[mi][ni] = mfma16(Af[mi][kt], Bf[ni][kt], acc[mi][ni]);
        __builtin_amdgcn_s_setprio(0);
        __builtin_amdgcn_sched_barrier(0);

        // ---- phase 1: stage B-half of next tile; read A(MH=1); 32 MFMA ----
        if (st) {
            #pragma unroll
            for (int i = 0; i < 4; ++i) stage_slot(32 + w*4 + i, t + 1, nx);
        }
        #pragma unroll
        for (int mi = 0; mi < 4; ++mi)
            #pragma unroll
            for (int kt = 0; kt < 2; ++kt)
                Af[mi][kt] = *reinterpret_cast<const bf16x8*>(
                    &ab[cur][(size_t)((wr*8 + 4 + mi)*2 + kt)*512 + (size_t)lane*8]);
        asm volatile("s_waitcnt lgkmcnt(0)" ::: "memory");
        __builtin_amdgcn_sched_barrier(0);
        __builtin_amdgcn_s_setprio(1);
        #pragma unroll
        for (int kt = 0; kt < 2; ++kt)
            #pragma unroll
            for (int ni = 0; ni < 4; ++ni)
                #pragma unroll
                for (int mi = 0; mi < 4; ++mi)
                    acc[4 + mi][ni] = mfma16(Af[mi][kt], Bf[ni][kt], acc[4 + mi][ni]);
        __builtin_amdgcn_s_setprio(0);
        __builtin_amdgcn_sched_barrier(0);

        // ---- tile boundary: drain staging (>=1 phase old), swap buffers ----
        if (st) {
            asm volatile("s_waitcnt vmcnt(0)" ::: "memory");
            __builtin_amdgcn_sched_barrier(0);
            __builtin_amdgcn_s_barrier();
        }
    }

    // epilogue: silu + dot W3 -> per-row energy; rows: wr*128 + mi*16 + l4*4 + r
    {
        float e16[8][4];
        #pragma unroll
        for (int mi = 0; mi < 8; ++mi)
            #pragma unroll
            for (int r = 0; r < 4; ++r) e16[mi][r] = 0.0f;

        #pragma unroll
        for (int ni = 0; ni < 4; ++ni) {
            int col = cb*256 + wc*64 + ni*16 + l15;
            float bias = b2[col];
            float w3v  = w3[col];
            #pragma unroll
            for (int mi = 0; mi < 8; ++mi)
                #pragma unroll
                for (int r = 0; r < 4; ++r)
                    e16[mi][r] += silu_f(acc[mi][ni][r] + bias) * w3v;
        }

        // reduce across the 16 col-lanes (keeps l4 intact)
        #pragma unroll
        for (int off = 1; off < 16; off <<= 1)
            #pragma unroll
            for (int mi = 0; mi < 8; ++mi)
                #pragma unroll
                for (int r = 0; r < 4; ++r)
                    e16[mi][r] += __shfl_xor(e16[mi][r], off, 64);

        if (l15 == 0) {
            #pragma unroll
            for (int mi = 0; mi < 8; ++mi)
                #pragma unroll
                for (int r = 0; r < 4; ++r)
                    e_red[w][mi*16 + l4*4 + r] = e16[mi][r];
        }
    }
    __syncthreads();

    // fold 4 wc-partials per row; threads 0..255 handle the 256 rows
    if (tid < 256) {
        const int wrg = tid >> 7;
        const int rr  = tid & 127;
        float s = 0.0f;
        #pragma unroll
        for (int wci = 0; wci < 4; ++wci) s += e_red[wrg*4 + wci][rr];
        e_part[(size_t)cb * NROWS + (size_t)rb * 256 + wrg*128 + rr] = s;
    }
}

// ---------- deterministic segment sum over sorted batch, folding 4 cb slabs + b3 ----------
__global__ void segsum(const float* __restrict__ e_part,
                       const int* __restrict__ batch,
                       const float* __restrict__ b3,
                       float* __restrict__ out)
{
    int mol  = blockIdx.x;
    int lane = threadIdx.x;          // 64 threads

    int lo = 0, hi = NROWS;
    while (lo < hi) { int mid = (lo + hi) >> 1; if (batch[mid] < mol)     lo = mid + 1; else hi = mid; }
    int start = lo;
    lo = start; hi = NROWS;
    while (lo < hi) { int mid = (lo + hi) >> 1; if (batch[mid] < mol + 1) lo = mid + 1; else hi = mid; }
    int end = lo;

    float b3v = b3[0];
    float s = 0.0f;
    for (int i = start + lane; i < end; i += 64) {
        float v = b3v;
        #pragma unroll
        for (int sl = 0; sl < 4; ++sl) v += e_part[(size_t)sl * NROWS + i];
        s += v;
    }
    #pragma unroll
    for (int off = 32; off; off >>= 1) s += __shfl_xor(s, off, 64);
    if (lane == 0) out[mol] = s;
}

// ---------- launch ----------
extern "C" void kernel_launch(void* const* d_in, const int* in_sizes, int n_in,
                              void* d_out, int out_size, void* d_ws, size_t ws_size,
                              hipStream_t stream) {
    const float* emb = (const float*)d_in[0];
    const float* W1  = (const float*)d_in[1];
    const float* b1  = (const float*)d_in[2];
    const float* W2  = (const float*)d_in[3];
    const float* b2  = (const float*)d_in[4];
    const float* W3  = (const float*)d_in[5];
    const float* b3  = (const float*)d_in[6];
    const int*   batch = (const int*)d_in[7];

    char* ws = (char*)d_ws;
    u16*   w1f    = (u16*)ws;                                  // 256 KB (32x32 frags)
    u16*   w2f    = (u16*)(ws + 262144);                       // 2 MB  (16x16 frags)
    u16*   h1f    = (u16*)(ws + 2359296);                      // 256 MB (16x16 A-frags)
    float* e_part = (float*)(ws + 2359296 + 268435456);        // 2 MB (4 slabs)

    pack_w32<<<64,  256, 0, stream>>>(W1, w1f, CIN,  HDIM);
    pack_w16<<<512, 256, 0, stream>>>(W2, w2f, HDIM, HDIM);
    gemm1_pack<<<NROWS / 64, 512, 0, stream>>>(emb, w1f, b1, h1f);
    gemm2_energy<<<NRB * NCB, 512, 0, stream>>>(h1f, w2f, b2, W3, e_part);
    segsum<<<NMOL, 64, 0, stream>>>(e_part, batch, b3, (float*)d_out);
}